// Round 7
// baseline (187.297 us; speedup 1.0000x reference)
//
#include <hip/hip_runtime.h>

// Batched Thomas solve, B=2048 rows, N=8192, fp32 — SCAN-FREE, CH=16.
//
// R11 vs R10 (post-mortem: spill finally gone (WRITE=output exact, FETCH
// 34MB) but dur stuck at 65us with VALUBusy 13.5%, occupancy 26.7%. VALU
// work is only ~9us; the kernel is LOAD-LATENCY-SERIALIZED: 64-float
// cpv/dpv in the unified file -> ~130 effective regs -> only ~2-4 waves/EU,
// and ~36 dependent float4 loads/thread x ~500cy can't be overlapped.
// waves_per_eu(2,4)'s max=4 cap hurt.)
// Fix: CH 32->16, TB 256->512 (block = row). Live set = cpv[16]+dpv[16]=32
// floats + state + staging ~ 62 regs -> fits the 64-reg point the allocator
// has targeted all session => 8 waves/EU (2-4x concurrency), and loads/
// thread drop 36->26. Redundancy rises to 3.5x reads/output, but those are
// cheap streaming FMAs + L1/L2-hit loads.
//
// Numerics (same bounds as R9/R10, passed twice): alpha in [0,0.3) =>
// forward influence decays x14/elem (MF=8 warm-up, err ~1e-9); backward
// |cp| <= 0.738 (MB=32 tail, worst-case ~1e-3 << tol 0.015625). Row edges
// exact. MB > CH now: tail is clamped at row end (ng groups); final tail
// step takes ap1=0 == the exact c_{N-1}=0 boundary for t=TB-2, and provably
// harmless for interior threads (last step's cp only feeds prod, never
// used again). No barriers/shuffles/LDS.

#define NN 8192
#define TB 512
#define CH 16          // NN / TB outputs per thread
#define MF 8           // forward warm-up elements
#define MB 32          // backward tail elements

__device__ __forceinline__ float frcp(float x) { return __builtin_amdgcn_rcpf(x); }

// One forward Thomas step at position j.
//   carries: cp, dp, sqm (= alpha_{j-1}^2), a0 (= alpha_j), sq0 (= alpha_j^2)
//   inputs:  AP1 = alpha_{j+1}, FJ = f_j
#define FSTEP_CORE(AP1, FJ)                                \
    const float ap1 = (AP1);                               \
    const float sqp = ap1 * ap1;                           \
    const float c   = __builtin_fmaf(ap1, 2.0f, sqp);      \
    const float b   = __builtin_fmaf(sq0, a0, 1.0f);       \
    const float den = __builtin_fmaf(-sqm, cp, b);         \
    const float rd  = frcp(den);                           \
    cp = c * rd;                                           \
    dp = __builtin_fmaf(-sqm, dp, (FJ)) * rd;              \
    sqm = sq0; a0 = ap1; sq0 = sqp;

#define WSTEP(AP1, FJ) { FSTEP_CORE(AP1, FJ) }

__global__ __launch_bounds__(TB, 8)
void thomas_trunc_kernel(const float* __restrict__ alpha,
                         const float* __restrict__ fvec,
                         float* __restrict__ out)
{
    const int t   = threadIdx.x;
    const int row = blockIdx.x;
    const float* __restrict__ arow = alpha + (size_t)row * NN;
    const int base = t * CH;

    // forward rolling state
    float cp = 0.f, dp = 0.f;
    float a0, sq0, sqm;

    const float aB = arow[base];

    // ---- warm-up over [base-MF, base): converges cp,dp to ~1e-9 ----
    if (t > 0) {
        const float am9 = arow[base - MF - 1];
        const float4* w4 = reinterpret_cast<const float4*>(arow + base - MF);
        const float4* g4 = reinterpret_cast<const float4*>(fvec + base - MF);
        const float4 W0 = w4[0], W1 = w4[1];
        const float4 G0 = g4[0], G1 = g4[1];
        sqm = am9 * am9;
        a0  = W0.x; sq0 = a0 * a0;
        WSTEP(W0.y, G0.x) WSTEP(W0.z, G0.y) WSTEP(W0.w, G0.z) WSTEP(W1.x, G0.w)
        WSTEP(W1.y, G1.x) WSTEP(W1.z, G1.y) WSTEP(W1.w, G1.z) WSTEP(aB,   G1.w)
    } else {
        sqm = 0.f;          // a_0 = 0 (true boundary)
        a0  = aB; sq0 = aB * aB;
    }

    // ---- chunk: CH exact-algorithm steps, cp/dp kept in registers ----
    float cpv[CH], dpv[CH];
    const float peek = (t < TB - 1) ? arow[base + CH] : 0.f;  // c_{N-1} = 0
    {
        const float4* a4 = reinterpret_cast<const float4*>(arow + base);
        const float4* f4 = reinterpret_cast<const float4*>(fvec + base);
        float4 aq = a4[0];
        #pragma unroll
        for (int g = 0; g < CH / 4; ++g) {
            const float4 fq  = f4[g];
            const float4 aqn = (g < CH / 4 - 1) ? a4[g + 1]
                                                : make_float4(peek, 0.f, 0.f, 0.f);
            { FSTEP_CORE(aq.y,  fq.x) cpv[4*g+0] = cp; dpv[4*g+0] = dp; }
            { FSTEP_CORE(aq.z,  fq.y) cpv[4*g+1] = cp; dpv[4*g+1] = dp; }
            { FSTEP_CORE(aq.w,  fq.z) cpv[4*g+2] = cp; dpv[4*g+2] = dp; }
            { FSTEP_CORE(aqn.x, fq.w) cpv[4*g+3] = cp; dpv[4*g+3] = dp; }
            aq = aqn;
        }
    }

    // ---- tail: up to MB forward steps, accumulating u_in on the fly ----
    // u_{base+CH} = sum_j (prod_{l<j} -cp_l) * dp_j, truncated after MB
    // or clamped at the row end (where truncation becomes EXACT: u_N = 0).
    float u = 0.f;
    if (t < TB - 1) {
        int tail_len = NN - base - CH;                // 16 for t=TB-2, else >=32
        if (tail_len > MB) tail_len = MB;
        const int ng = tail_len >> 2;                 // 4 or 8 groups
        const float4* a4 = reinterpret_cast<const float4*>(arow + base + CH);
        const float4* f4 = reinterpret_cast<const float4*>(fvec + base + CH);
        float prod = 1.f, uacc = 0.f;
        float4 aq = a4[0];   // aq.x == alpha[base+CH] == current a0 carry
        #pragma unroll
        for (int g = 0; g < MB / 4; ++g) {
            if (g < ng) {
                const float4 fq  = f4[g];
                const float4 aqn = (g + 1 < ng) ? a4[g + 1]
                                                : make_float4(0.f, 0.f, 0.f, 0.f);
                { FSTEP_CORE(aq.y,  fq.x) uacc = __builtin_fmaf(prod, dp, uacc); prod = prod * (-cp); }
                { FSTEP_CORE(aq.z,  fq.y) uacc = __builtin_fmaf(prod, dp, uacc); prod = prod * (-cp); }
                { FSTEP_CORE(aq.w,  fq.z) uacc = __builtin_fmaf(prod, dp, uacc); prod = prod * (-cp); }
                { FSTEP_CORE(aqn.x, fq.w) uacc = __builtin_fmaf(prod, dp, uacc); prod = prod * (-cp); }
                aq = aqn;
            }
        }
        u = uacc;
    }
    // t == TB-1: u_in = 0 exactly (true boundary u_N = 0)

    // ---- back-substitution from registers + float4 stores ----
    float4* o4 = reinterpret_cast<float4*>(out + (size_t)row * NN + base);
    #pragma unroll
    for (int g = CH / 4 - 1; g >= 0; --g) {
        const float u3 = __builtin_fmaf(-cpv[4*g+3], u,  dpv[4*g+3]);
        const float u2 = __builtin_fmaf(-cpv[4*g+2], u3, dpv[4*g+2]);
        const float u1 = __builtin_fmaf(-cpv[4*g+1], u2, dpv[4*g+1]);
        const float u0 = __builtin_fmaf(-cpv[4*g+0], u1, dpv[4*g+0]);
        o4[g] = make_float4(u0, u1, u2, u3);
        u = u0;
    }
}

extern "C" void kernel_launch(void* const* d_in, const int* in_sizes, int n_in,
                              void* d_out, int out_size, void* d_ws, size_t ws_size,
                              hipStream_t stream) {
    const float* alpha = (const float*)d_in[0];
    const float* fvec  = (const float*)d_in[1];
    float* out = (float*)d_out;
    const int nrows = out_size / NN;   // 2048
    thomas_trunc_kernel<<<nrows, TB, 0, stream>>>(alpha, fvec, out);
}

// Round 8
// 144.656 us; speedup vs baseline: 1.2948x; 1.2948x over previous
//
#include <hip/hip_runtime.h>

// Batched Thomas solve, B=2048 rows, N=8192, fp32 — SCAN-FREE, arrays in LDS.
//
// R12 vs R11 (post-mortem: requesting 8 waves/EU (launch_bounds(512,8)) made
// the allocator squeeze to VGPR_Count=32 and dump BOTH 16-float arrays to
// scratch: WRITE 218MB (=output+154MB spill), FETCH 102MB, dur 104us, BW-
// bound on spill traffic. Session rule, now 4-for-4: this compiler will NOT
// keep a >=16-float per-thread array in registers at the 64-reg point.)
// Fix: scan-free algorithm (R10) + the one storage scheme proven spill-free
// for arrays (R8): LDS [k][t], conflict-free (64 lanes x consecutive 4B =
// 2 lanes/bank), threads touch only their own slots => ZERO barriers.
//  - s_cpv[16][512] + s_dpv[16][512] = 64 KiB => 2 blocks/CU, 16 waves/CU
//    (2x R10's concurrency); registers ~35 live => no spill pressure at all.
//  - No launch_bounds reg games: LDS is what caps occupancy, allocator has
//    slack. Freed regs let the scheduler hoist the independent float4 loads
//    (R10's serialized latency).
//
// Numerics (identical to R9-R11, passed 3x): alpha in [0,0.3) => forward
// influence decays x14/elem (MF=8 warm-up, err ~1e-9); backward |cp|<=0.738
// (MB=32 tail, worst-case ~1e-3 << tol). Row edges exact; tail clamped at
// row end where truncation is exact (u_N = 0).

#define NN 8192
#define TB 512
#define CH 16          // NN / TB outputs per thread
#define MF 8           // forward warm-up elements
#define MB 32          // backward tail elements

__device__ __forceinline__ float frcp(float x) { return __builtin_amdgcn_rcpf(x); }

// One forward Thomas step at position j.
//   carries: cp, dp, sqm (= alpha_{j-1}^2), a0 (= alpha_j), sq0 (= alpha_j^2)
//   inputs:  AP1 = alpha_{j+1}, FJ = f_j
#define FSTEP_CORE(AP1, FJ)                                \
    const float ap1 = (AP1);                               \
    const float sqp = ap1 * ap1;                           \
    const float c   = __builtin_fmaf(ap1, 2.0f, sqp);      \
    const float b   = __builtin_fmaf(sq0, a0, 1.0f);       \
    const float den = __builtin_fmaf(-sqm, cp, b);         \
    const float rd  = frcp(den);                           \
    cp = c * rd;                                           \
    dp = __builtin_fmaf(-sqm, dp, (FJ)) * rd;              \
    sqm = sq0; a0 = ap1; sq0 = sqp;

#define WSTEP(AP1, FJ) { FSTEP_CORE(AP1, FJ) }

__global__ __launch_bounds__(TB)
void thomas_trunc_kernel(const float* __restrict__ alpha,
                         const float* __restrict__ fvec,
                         float* __restrict__ out)
{
    __shared__ float s_cpv[CH][TB];   // 32 KiB
    __shared__ float s_dpv[CH][TB];   // 32 KiB

    const int t   = threadIdx.x;
    const int row = blockIdx.x;
    const float* __restrict__ arow = alpha + (size_t)row * NN;
    const int base = t * CH;

    // forward rolling state
    float cp = 0.f, dp = 0.f;
    float a0, sq0, sqm;

    const float aB = arow[base];

    // ---- warm-up over [base-MF, base): converges cp,dp to ~1e-9 ----
    if (t > 0) {
        const float am9 = arow[base - MF - 1];
        const float4* w4 = reinterpret_cast<const float4*>(arow + base - MF);
        const float4* g4 = reinterpret_cast<const float4*>(fvec + base - MF);
        const float4 W0 = w4[0], W1 = w4[1];
        const float4 G0 = g4[0], G1 = g4[1];
        sqm = am9 * am9;
        a0  = W0.x; sq0 = a0 * a0;
        WSTEP(W0.y, G0.x) WSTEP(W0.z, G0.y) WSTEP(W0.w, G0.z) WSTEP(W1.x, G0.w)
        WSTEP(W1.y, G1.x) WSTEP(W1.z, G1.y) WSTEP(W1.w, G1.z) WSTEP(aB,   G1.w)
    } else {
        sqm = 0.f;          // a_0 = 0 (true boundary)
        a0  = aB; sq0 = aB * aB;
    }

    // ---- chunk: CH exact-algorithm steps; cp/dp streamed into LDS ----
    const float peek = (t < TB - 1) ? arow[base + CH] : 0.f;  // c_{N-1} = 0
    {
        const float4* a4 = reinterpret_cast<const float4*>(arow + base);
        const float4* f4 = reinterpret_cast<const float4*>(fvec + base);
        float4 aq = a4[0];
        #pragma unroll
        for (int g = 0; g < CH / 4; ++g) {
            const float4 fq  = f4[g];
            const float4 aqn = (g < CH / 4 - 1) ? a4[g + 1]
                                                : make_float4(peek, 0.f, 0.f, 0.f);
            { FSTEP_CORE(aq.y,  fq.x) s_cpv[4*g+0][t] = cp; s_dpv[4*g+0][t] = dp; }
            { FSTEP_CORE(aq.z,  fq.y) s_cpv[4*g+1][t] = cp; s_dpv[4*g+1][t] = dp; }
            { FSTEP_CORE(aq.w,  fq.z) s_cpv[4*g+2][t] = cp; s_dpv[4*g+2][t] = dp; }
            { FSTEP_CORE(aqn.x, fq.w) s_cpv[4*g+3][t] = cp; s_dpv[4*g+3][t] = dp; }
            aq = aqn;
        }
    }

    // ---- tail: up to MB forward steps, accumulating u_in on the fly ----
    // u_{base+CH} = sum_j (prod_{l<j} -cp_l) * dp_j, truncated after MB
    // or clamped at the row end (where truncation becomes EXACT: u_N = 0).
    float u = 0.f;
    if (t < TB - 1) {
        int tail_len = NN - base - CH;                // 16 for t=TB-2, else >=32
        if (tail_len > MB) tail_len = MB;
        const int ng = tail_len >> 2;                 // 4 or 8 groups
        const float4* a4 = reinterpret_cast<const float4*>(arow + base + CH);
        const float4* f4 = reinterpret_cast<const float4*>(fvec + base + CH);
        float prod = 1.f, uacc = 0.f;
        float4 aq = a4[0];   // aq.x == alpha[base+CH] == current a0 carry
        #pragma unroll
        for (int g = 0; g < MB / 4; ++g) {
            if (g < ng) {
                const float4 fq  = f4[g];
                const float4 aqn = (g + 1 < ng) ? a4[g + 1]
                                                : make_float4(0.f, 0.f, 0.f, 0.f);
                { FSTEP_CORE(aq.y,  fq.x) uacc = __builtin_fmaf(prod, dp, uacc); prod = prod * (-cp); }
                { FSTEP_CORE(aq.z,  fq.y) uacc = __builtin_fmaf(prod, dp, uacc); prod = prod * (-cp); }
                { FSTEP_CORE(aq.w,  fq.z) uacc = __builtin_fmaf(prod, dp, uacc); prod = prod * (-cp); }
                { FSTEP_CORE(aqn.x, fq.w) uacc = __builtin_fmaf(prod, dp, uacc); prod = prod * (-cp); }
                aq = aqn;
            }
        }
        u = uacc;
    }
    // t == TB-1: u_in = 0 exactly (true boundary u_N = 0)

    // ---- back-substitution from LDS + float4 stores ----
    float4* o4 = reinterpret_cast<float4*>(out + (size_t)row * NN + base);
    #pragma unroll
    for (int g = CH / 4 - 1; g >= 0; --g) {
        const float u3 = __builtin_fmaf(-s_cpv[4*g+3][t], u,  s_dpv[4*g+3][t]);
        const float u2 = __builtin_fmaf(-s_cpv[4*g+2][t], u3, s_dpv[4*g+2][t]);
        const float u1 = __builtin_fmaf(-s_cpv[4*g+1][t], u2, s_dpv[4*g+1][t]);
        const float u0 = __builtin_fmaf(-s_cpv[4*g+0][t], u1, s_dpv[4*g+0][t]);
        o4[g] = make_float4(u0, u1, u2, u3);
        u = u0;
    }
}

extern "C" void kernel_launch(void* const* d_in, const int* in_sizes, int n_in,
                              void* d_out, int out_size, void* d_ws, size_t ws_size,
                              hipStream_t stream) {
    const float* alpha = (const float*)d_in[0];
    const float* fvec  = (const float*)d_in[1];
    float* out = (float*)d_out;
    const int nrows = out_size / NN;   // 2048
    thomas_trunc_kernel<<<nrows, TB, 0, stream>>>(alpha, fvec, out);
}